// Round 12
// baseline (700.444 us; speedup 1.0000x reference)
//
#include <hip/hip_runtime.h>

#define NPTS   8192
#define NBATCH 16
#define NGROUP 512
#define GSIZE  32
#define BIGF   1e10f

typedef unsigned long long u64;
typedef float f32x2 __attribute__((ext_vector_type(2)));

// Packed fp32 ops via inline asm (VOP3P, gfx90a+; IEEE-rn per half — each
// half bit-identical to the scalar v_add_f32/v_mul_f32). ext_vector math
// scalarizes (r7); asm forces the packed encoding (proven working in r10).
__device__ __forceinline__ f32x2 pk_add(f32x2 a, f32x2 b) {
    f32x2 d;
    asm("v_pk_add_f32 %0, %1, %2" : "=v"(d) : "v"(a), "v"(b));
    return d;
}
__device__ __forceinline__ f32x2 pk_mul(f32x2 a, f32x2 b) {
    f32x2 d;
    asm("v_pk_mul_f32 %0, %1, %2" : "=v"(d) : "v"(a), "v"(b));
    return d;
}

// DPP max on a packed u64 key (round-7 proven): shift both 32-bit halves,
// compare-select. bound_ctrl=true injects key=0 which loses vs any real
// candidate (val>=0, distinct indices), so it's inert.
template <int CTRL>
__device__ __forceinline__ u64 dpp_max_u64(u64 k) {
    const unsigned lo  = (unsigned)k;
    const unsigned hi  = (unsigned)(k >> 32);
    const unsigned slo = (unsigned)__builtin_amdgcn_update_dpp(0, (int)lo, CTRL, 0xF, 0xF, true);
    const unsigned shi = (unsigned)__builtin_amdgcn_update_dpp(0, (int)hi, CTRL, 0xF, 0xF, true);
    const u64 s = ((u64)shi << 32) | slo;
    return s > k ? s : k;
}

__device__ __forceinline__ u64 umax64(u64 a, u64 b) { return a > b ? a : b; }

// wave-uniform 64-bit readlane (SALU path, no LDS pipe)
__device__ __forceinline__ u64 rdlane64(u64 v, int l) {
    const unsigned lo = (unsigned)__builtin_amdgcn_readlane((int)(unsigned)v, l);
    const unsigned hi = (unsigned)__builtin_amdgcn_readlane((int)(unsigned)(v >> 32), l);
    return ((u64)hi << 32) | lo;
}

// ---------------------------------------------------------------------------
// Kernel 1: farthest point sampling + fused prepack (r11 structure, 543us).
// Round-12 change: ONLY the dist arithmetic goes packed (asm v_pk_*), 8 pairs
// instead of 16 scalars; tracking and the single u64-DPP tail stay r7-exact
// (r10 showed tail restructures add serial latency). Bit-identical d values:
// x+(-L) == x-L, pk halves are rn. Selection order unchanged.
// ---------------------------------------------------------------------------
__global__ __launch_bounds__(512) void fps_kernel(const float* __restrict__ pc,
                                                  int* __restrict__ rep,
                                                  float4* __restrict__ ws4) {
    const int b    = blockIdx.x;
    const int t    = threadIdx.x;
    const int lane = t & 63;
    const int w    = t >> 6;

    __shared__ float4 sp[NPTS];                      // 128 KB
    __shared__ __align__(16) u64 keys[2][8];
    __shared__ int lrep[NGROUP];                     // 2 KB

    const float* base = pc + (size_t)b * NPTS * 6;
    float4* w4 = ws4 + ((size_t)b << 13);

    f32x2 px[8], py[8], pz[8], dmin[8];
#pragma unroll
    for (int j = 0; j < 8; ++j) {
        const int p0 = t * 16 + 2 * j;
        const float x0 = base[p0 * 6 + 0], y0 = base[p0 * 6 + 1], z0 = base[p0 * 6 + 2];
        const float x1 = base[p0 * 6 + 6], y1 = base[p0 * 6 + 7], z1 = base[p0 * 6 + 8];
        px[j] = (f32x2){x0, x1};
        py[j] = (f32x2){y0, y1};
        pz[j] = (f32x2){z0, z1};
        const float4 f0 = make_float4(x0, y0, z0, 0.0f);
        const float4 f1 = make_float4(x1, y1, z1, 0.0f);
        sp[p0]     = f0;  w4[p0]     = f0;           // LDS + fused prepack
        sp[p0 + 1] = f1;  w4[p0 + 1] = f1;
        dmin[j] = (f32x2){BIGF, BIGF};
    }
    __syncthreads();

    const int tb = t * 16;
    int last = 0;
    for (int k = 0; k < NGROUP; ++k) {
        if (t == 0) lrep[k] = last;
        if (k == NGROUP - 1) break;

        const float4 L = sp[last];                   // one ds_read_b128, broadcast
        const f32x2 nLx = (f32x2){-L.x, -L.x};
        const f32x2 nLy = (f32x2){-L.y, -L.y};
        const f32x2 nLz = (f32x2){-L.z, -L.z};

        float bv = -1.0f;
        int   bi = 0;
#pragma unroll
        for (int j = 0; j < 8; ++j) {
            const f32x2 dx = pk_add(px[j], nLx);     // x + (-L) == x - L exactly
            const f32x2 dy = pk_add(py[j], nLy);
            const f32x2 dz = pk_add(pz[j], nLz);
            const f32x2 xx = pk_mul(dx, dx);
            const f32x2 yy = pk_mul(dy, dy);
            const f32x2 zz = pk_mul(dz, dz);
            const f32x2 d  = pk_add(pk_add(xx, yy), zz);   // ((x^2+y^2)+z^2), rn
            f32x2 dm;
            dm.x = fminf(dmin[j].x, d.x);
            dm.y = fminf(dmin[j].y, d.y);
            dmin[j] = dm;
            if (dm.x > bv) { bv = dm.x; bi = tb + 2 * j; }      // strict >
            if (dm.y > bv) { bv = dm.y; bi = tb + 2 * j + 1; }  // keeps lowest idx
        }

        u64 key = ((u64)__float_as_uint(bv) << 13) | (unsigned)(8191 - bi);
        key = dpp_max_u64<0x111>(key);   // row_shr:1
        key = dpp_max_u64<0x112>(key);   // row_shr:2
        key = dpp_max_u64<0x114>(key);   // row_shr:4
        key = dpp_max_u64<0x118>(key);   // row_shr:8
        key = dpp_max_u64<0x142>(key);   // row_bcast:15
        key = dpp_max_u64<0x143>(key);   // row_bcast:31 -> lane 63 = wave max

        const int buf = k & 1;                       // parity dbuf -> 1 barrier/iter
        if (lane == 63) keys[buf][w] = key;
        __syncthreads();

        const ulonglong2* kp = (const ulonglong2*)keys[buf];   // 4x ds_read_b128
        const ulonglong2 k0 = kp[0], k1 = kp[1], k2 = kp[2], k3 = kp[3];
        const u64 best = umax64(umax64(umax64(k0.x, k0.y), umax64(k1.x, k1.y)),
                                umax64(umax64(k2.x, k2.y), umax64(k3.x, k3.y)));
        last = 8191 - (int)(best & 0x1FFFull);
    }

    __syncthreads();                                 // lrep visibility
    for (int j = t; j < NGROUP; j += 512)            // one coalesced write-out
        rep[b * NGROUP + j] = lrep[j];
}

// ---------------------------------------------------------------------------
// Kernel 2: 32-NN per sampled center + gathers (round-11, passing, ~110us).
// u64 keys (f64 bit order), readlane broadcasts, 2 points/lane/iter.
// ---------------------------------------------------------------------------
__global__ __launch_bounds__(256) void knn_kernel(const float* __restrict__ pc,
                                                  const float4* __restrict__ ws4,
                                                  const int* __restrict__ rep,
                                                  float* __restrict__ out) {
    const int tid  = threadIdx.x;
    const int lane = tid & 63;
    const int w    = tid >> 6;
    const int q    = blockIdx.x * 4 + w;       // 0 .. 8191
    const int b    = q >> 9;

    const float*  base  = pc  + (size_t)b * NPTS * 6;
    const float4* base4 = ws4 + ((size_t)b << 13);
    const int     r     = rep[q];

    const float4 Q = base4[r];
    const float qxf = Q.x, qyf = Q.y, qzf = Q.z;
    const double qx = (double)qxf, qy = (double)qyf, qz = (double)qzf;

    const u64 INFB = 0x7ff0000000000000ull;
    u64 vk = INFB;  int vi = 0x7fffffff;       // lane-distributed sorted list
    u64 tauk = INFB;                           // 32nd element's key (uniform)

    for (int i = 0; i < NPTS / 128; ++i) {
        const int p0 = i * 128 + lane;
        const float4 T0 = base4[p0];
        const float4 T1 = base4[p0 + 64];

        const double dx0 = qx - (double)T0.x;
        const double dy0 = qy - (double)T0.y;
        const double dz0 = qz - (double)T0.z;
        const u64 kd0 = __double_as_longlong(dx0 * dx0 + dy0 * dy0 + dz0 * dz0);
        const double dx1 = qx - (double)T1.x;
        const double dy1 = qy - (double)T1.y;
        const double dz1 = qz - (double)T1.z;
        const u64 kd1 = __double_as_longlong(dx1 * dx1 + dy1 * dy1 + dz1 * dz1);

        u64 m0 = __ballot(kd0 < tauk);
        const u64 m1pre = __ballot(kd1 < tauk);

        if (m0 | m1pre) {
            while (m0) {
                const int l = __ffsll(m0) - 1;
                m0 &= m0 - 1;
                const u64 xk = rdlane64(kd0, l);   // SALU broadcast
                const int xi = i * 128 + l;        // affine: no shuffle
                const u64 pk = __shfl_up(vk, 1);
                const int pv = __shfl_up(vi, 1);
                const bool ltp = (lane > 0) && (xk < pk);
                const bool ltc = xk < vk;
                vk = ltp ? pk : (ltc ? xk : vk);
                vi = ltp ? pv : (ltc ? xi : vi);
            }
            tauk = rdlane64(vk, 31);               // refresh before half B
            u64 m1 = m1pre;
            while (m1) {
                const int l = __ffsll(m1) - 1;
                m1 &= m1 - 1;
                const u64 xk = rdlane64(kd1, l);
                if (xk < tauk) {                   // re-filter vs fresh tau
                    const int xi = i * 128 + 64 + l;
                    const u64 pk = __shfl_up(vk, 1);
                    const int pv = __shfl_up(vi, 1);
                    const bool ltp = (lane > 0) && (xk < pk);
                    const bool ltc = xk < vk;
                    vk = ltp ? pk : (ltc ? xk : vk);
                    vi = ltp ? pv : (ltc ? xi : vi);
                }
            }
            tauk = rdlane64(vk, 31);
        }
    }

    // ---- outputs ----
    const size_t NBH = (size_t)NBATCH * NGROUP * GSIZE * 6;   // neighborhood elems
    const size_t CEN = (size_t)NBATCH * NGROUP * 6;           // center elems

    if (lane == 0) {
#pragma unroll
        for (int c = 0; c < 6; ++c)
            out[NBH + (size_t)q * 6 + c] = base[r * 6 + c];
    }
    if (lane < GSIZE) {
        const int n = vi;                      // lane-sorted: position == lane
        out[NBH + CEN + (size_t)q * GSIZE + lane] = (float)n;

        const float* np_ = base + (size_t)n * 6;
        const size_t o = ((size_t)q * GSIZE + lane) * 6;
        out[o + 0] = __fsub_rn(np_[0], qxf);
        out[o + 1] = __fsub_rn(np_[1], qyf);
        out[o + 2] = __fsub_rn(np_[2], qzf);
        out[o + 3] = np_[3];
        out[o + 4] = np_[4];
        out[o + 5] = np_[5];
    }
}

extern "C" void kernel_launch(void* const* d_in, const int* in_sizes, int n_in,
                              void* d_out, int out_size, void* d_ws, size_t ws_size,
                              hipStream_t stream) {
    const float* pc  = (const float*)d_in[0];
    float*       out = (float*)d_out;
    int*         rep = (int*)d_ws;                              // 32 KB
    float4*      ws4 = (float4*)((char*)d_ws + 32 * 1024);      // 2 MB

    fps_kernel<<<NBATCH, 512, 0, stream>>>(pc, rep, ws4);
    knn_kernel<<<NBATCH * NGROUP / 4, 256, 0, stream>>>(pc, ws4, rep, out);
}

// Round 13
// 661.249 us; speedup vs baseline: 1.0593x; 1.0593x over previous
//
#include <hip/hip_runtime.h>

#define NPTS   8192
#define NBATCH 16
#define NGROUP 512
#define GSIZE  32
#define BIGF   1e10f

typedef unsigned long long u64;

// DPP max on a packed u64 key (round-7 proven): shift both 32-bit halves,
// compare-select. bound_ctrl=true injects key=0 which loses vs any real
// candidate (val>=0, distinct indices), so it's inert.
template <int CTRL>
__device__ __forceinline__ u64 dpp_max_u64(u64 k) {
    const unsigned lo  = (unsigned)k;
    const unsigned hi  = (unsigned)(k >> 32);
    const unsigned slo = (unsigned)__builtin_amdgcn_update_dpp(0, (int)lo, CTRL, 0xF, 0xF, true);
    const unsigned shi = (unsigned)__builtin_amdgcn_update_dpp(0, (int)hi, CTRL, 0xF, 0xF, true);
    const u64 s = ((u64)shi << 32) | slo;
    return s > k ? s : k;
}

__device__ __forceinline__ u64 umax64(u64 a, u64 b) { return a > b ? a : b; }

// wave-uniform 64-bit readlane (SALU path, no LDS pipe)
__device__ __forceinline__ u64 rdlane64(u64 v, int l) {
    const unsigned lo = (unsigned)__builtin_amdgcn_readlane((int)(unsigned)v, l);
    const unsigned hi = (unsigned)__builtin_amdgcn_readlane((int)(unsigned)(v >> 32), l);
    return ((u64)hi << 32) | lo;
}

// ---------------------------------------------------------------------------
// Kernel 1: farthest point sampling + fused prepack — ROUND-11 VERBATIM
// (543us; r10/r12 proved both pk-math and tail restructures regress).
// ---------------------------------------------------------------------------
__global__ __launch_bounds__(512) void fps_kernel(const float* __restrict__ pc,
                                                  int* __restrict__ rep,
                                                  float4* __restrict__ ws4) {
    const int b    = blockIdx.x;
    const int t    = threadIdx.x;
    const int lane = t & 63;
    const int w    = t >> 6;

    __shared__ float4 sp[NPTS];                      // 128 KB
    __shared__ __align__(16) u64 keys[2][8];
    __shared__ int lrep[NGROUP];                     // 2 KB

    const float* base = pc + (size_t)b * NPTS * 6;
    float4* w4 = ws4 + ((size_t)b << 13);

    float px[16], py[16], pz[16], dmin[16];
#pragma unroll
    for (int j = 0; j < 16; ++j) {
        const int p = t * 16 + j;
        const float x = base[p * 6 + 0];
        const float y = base[p * 6 + 1];
        const float z = base[p * 6 + 2];
        px[j] = x; py[j] = y; pz[j] = z;
        const float4 f = make_float4(x, y, z, 0.0f);
        sp[p] = f;
        w4[p] = f;                                   // fused prepack
        dmin[j] = BIGF;
    }
    __syncthreads();

    int last = 0;
    for (int k = 0; k < NGROUP; ++k) {
        if (t == 0) lrep[k] = last;
        if (k == NGROUP - 1) break;

        const float4 L = sp[last];                   // one ds_read_b128, broadcast

        float bv = -1.0f;
        int   bi = 0;
#pragma unroll
        for (int j = 0; j < 16; ++j) {
            const float dx = __fsub_rn(px[j], L.x);
            const float dy = __fsub_rn(py[j], L.y);
            const float dz = __fsub_rn(pz[j], L.z);
            // ((dx^2 + dy^2) + dz^2), no FMA -> matches numpy fp32 (verified)
            const float d = __fadd_rn(__fadd_rn(__fmul_rn(dx, dx),
                                                __fmul_rn(dy, dy)),
                                      __fmul_rn(dz, dz));
            const float dm = fminf(dmin[j], d);
            dmin[j] = dm;
            if (dm > bv) { bv = dm; bi = t * 16 + j; }   // strict > keeps lowest idx
        }

        u64 key = ((u64)__float_as_uint(bv) << 13) | (unsigned)(8191 - bi);
        key = dpp_max_u64<0x111>(key);   // row_shr:1
        key = dpp_max_u64<0x112>(key);   // row_shr:2
        key = dpp_max_u64<0x114>(key);   // row_shr:4
        key = dpp_max_u64<0x118>(key);   // row_shr:8
        key = dpp_max_u64<0x142>(key);   // row_bcast:15
        key = dpp_max_u64<0x143>(key);   // row_bcast:31 -> lane 63 = wave max

        const int buf = k & 1;                       // parity dbuf -> 1 barrier/iter
        if (lane == 63) keys[buf][w] = key;
        __syncthreads();

        const ulonglong2* kp = (const ulonglong2*)keys[buf];   // 4x ds_read_b128
        const ulonglong2 k0 = kp[0], k1 = kp[1], k2 = kp[2], k3 = kp[3];
        const u64 best = umax64(umax64(umax64(k0.x, k0.y), umax64(k1.x, k1.y)),
                                umax64(umax64(k2.x, k2.y), umax64(k3.x, k3.y)));
        last = 8191 - (int)(best & 0x1FFFull);
    }

    __syncthreads();                                 // lrep visibility
    for (int j = t; j < NGROUP; j += 512)            // one coalesced write-out
        rep[b * NGROUP + j] = lrep[j];
}

// ---------------------------------------------------------------------------
// Kernel 2: 32-NN per sampled center + gathers (r11 machinery + round-13
// fp32 pre-filter).
// Pre-filter: d2f in fp32 difference form (FMA ok, it's only a BOUND; rel
// err <= ~4e-7) vs tauf = (float)tau * (1+1e-5) (25x margin). If no lane's
// d2f <= tauf, the whole fp64 block is skipped (s_cbranch_execz): a skipped
// point provably has true d2 > tau, and tau only decreases, so it could
// never enter the list. All surviving candidates run the EXACT r11 fp64
// path -> selection bit-identical.
// ---------------------------------------------------------------------------
__global__ __launch_bounds__(256) void knn_kernel(const float* __restrict__ pc,
                                                  const float4* __restrict__ ws4,
                                                  const int* __restrict__ rep,
                                                  float* __restrict__ out) {
    const int tid  = threadIdx.x;
    const int lane = tid & 63;
    const int w    = tid >> 6;
    const int q    = blockIdx.x * 4 + w;       // 0 .. 8191
    const int b    = q >> 9;

    const float*  base  = pc  + (size_t)b * NPTS * 6;
    const float4* base4 = ws4 + ((size_t)b << 13);
    const int     r     = rep[q];

    const float4 Q = base4[r];
    const float qxf = Q.x, qyf = Q.y, qzf = Q.z;
    const double qx = (double)qxf, qy = (double)qyf, qz = (double)qzf;

    const u64 INFB = 0x7ff0000000000000ull;
    u64 vk = INFB;  int vi = 0x7fffffff;       // lane-distributed sorted list
    u64 tauk = INFB;                           // 32nd element's key (uniform)
    float tauf = __int_as_float(0x7f800000);   // fp32 upper bound of tau

    for (int i = 0; i < NPTS / 128; ++i) {
        const int p0 = i * 128 + lane;
        const float4 T0 = base4[p0];
        const float4 T1 = base4[p0 + 64];

        // fp32 pre-filter (bound only; contraction fine)
        const float fx0 = qxf - T0.x, fy0 = qyf - T0.y, fz0 = qzf - T0.z;
        const float fx1 = qxf - T1.x, fy1 = qyf - T1.y, fz1 = qzf - T1.z;
        const float d2f0 = fx0 * fx0 + fy0 * fy0 + fz0 * fz0;
        const float d2f1 = fx1 * fx1 + fy1 * fy1 + fz1 * fz1;
        if (!__any((d2f0 <= tauf) || (d2f1 <= tauf)))
            continue;                          // provably no candidate here

        const double dx0 = qx - (double)T0.x;
        const double dy0 = qy - (double)T0.y;
        const double dz0 = qz - (double)T0.z;
        const u64 kd0 = __double_as_longlong(dx0 * dx0 + dy0 * dy0 + dz0 * dz0);
        const double dx1 = qx - (double)T1.x;
        const double dy1 = qy - (double)T1.y;
        const double dz1 = qz - (double)T1.z;
        const u64 kd1 = __double_as_longlong(dx1 * dx1 + dy1 * dy1 + dz1 * dz1);

        u64 m0 = __ballot(kd0 < tauk);
        const u64 m1pre = __ballot(kd1 < tauk);

        if (m0 | m1pre) {
            while (m0) {
                const int l = __ffsll(m0) - 1;
                m0 &= m0 - 1;
                const u64 xk = rdlane64(kd0, l);   // SALU broadcast
                const int xi = i * 128 + l;        // affine: no shuffle
                const u64 pk = __shfl_up(vk, 1);
                const int pv = __shfl_up(vi, 1);
                const bool ltp = (lane > 0) && (xk < pk);
                const bool ltc = xk < vk;
                vk = ltp ? pk : (ltc ? xk : vk);
                vi = ltp ? pv : (ltc ? xi : vi);
            }
            tauk = rdlane64(vk, 31);               // refresh before half B
            u64 m1 = m1pre;
            while (m1) {
                const int l = __ffsll(m1) - 1;
                m1 &= m1 - 1;
                const u64 xk = rdlane64(kd1, l);
                if (xk < tauk) {                   // re-filter vs fresh tau
                    const int xi = i * 128 + 64 + l;
                    const u64 pk = __shfl_up(vk, 1);
                    const int pv = __shfl_up(vi, 1);
                    const bool ltp = (lane > 0) && (xk < pk);
                    const bool ltc = xk < vk;
                    vk = ltp ? pk : (ltc ? xk : vk);
                    vi = ltp ? pv : (ltc ? xi : vi);
                }
            }
            tauk = rdlane64(vk, 31);
            tauf = (float)__longlong_as_double(tauk) * (1.0f + 1e-5f);
        }
    }

    // ---- outputs ----
    const size_t NBH = (size_t)NBATCH * NGROUP * GSIZE * 6;   // neighborhood elems
    const size_t CEN = (size_t)NBATCH * NGROUP * 6;           // center elems

    if (lane == 0) {
#pragma unroll
        for (int c = 0; c < 6; ++c)
            out[NBH + (size_t)q * 6 + c] = base[r * 6 + c];
    }
    if (lane < GSIZE) {
        const int n = vi;                      // lane-sorted: position == lane
        out[NBH + CEN + (size_t)q * GSIZE + lane] = (float)n;

        const float* np_ = base + (size_t)n * 6;
        const size_t o = ((size_t)q * GSIZE + lane) * 6;
        out[o + 0] = __fsub_rn(np_[0], qxf);
        out[o + 1] = __fsub_rn(np_[1], qyf);
        out[o + 2] = __fsub_rn(np_[2], qzf);
        out[o + 3] = np_[3];
        out[o + 4] = np_[4];
        out[o + 5] = np_[5];
    }
}

extern "C" void kernel_launch(void* const* d_in, const int* in_sizes, int n_in,
                              void* d_out, int out_size, void* d_ws, size_t ws_size,
                              hipStream_t stream) {
    const float* pc  = (const float*)d_in[0];
    float*       out = (float*)d_out;
    int*         rep = (int*)d_ws;                              // 32 KB
    float4*      ws4 = (float4*)((char*)d_ws + 32 * 1024);      // 2 MB

    fps_kernel<<<NBATCH, 512, 0, stream>>>(pc, rep, ws4);
    knn_kernel<<<NBATCH * NGROUP / 4, 256, 0, stream>>>(pc, ws4, rep, out);
}

// Round 14
// 653.255 us; speedup vs baseline: 1.0722x; 1.0122x over previous
//
#include <hip/hip_runtime.h>

#define NPTS   8192
#define NBATCH 16
#define NGROUP 512
#define GSIZE  32
#define BIGF   1e10f

typedef unsigned long long u64;

// DPP max on a packed u64 key (round-7 proven): shift both 32-bit halves,
// compare-select. bound_ctrl=true injects key=0 which loses vs any real
// candidate (val>=0, distinct indices), so it's inert.
template <int CTRL>
__device__ __forceinline__ u64 dpp_max_u64(u64 k) {
    const unsigned lo  = (unsigned)k;
    const unsigned hi  = (unsigned)(k >> 32);
    const unsigned slo = (unsigned)__builtin_amdgcn_update_dpp(0, (int)lo, CTRL, 0xF, 0xF, true);
    const unsigned shi = (unsigned)__builtin_amdgcn_update_dpp(0, (int)hi, CTRL, 0xF, 0xF, true);
    const u64 s = ((u64)shi << 32) | slo;
    return s > k ? s : k;
}

__device__ __forceinline__ u64 umax64(u64 a, u64 b) { return a > b ? a : b; }

// wave-uniform 64-bit readlane (SALU path, no LDS pipe)
__device__ __forceinline__ u64 rdlane64(u64 v, int l) {
    const unsigned lo = (unsigned)__builtin_amdgcn_readlane((int)(unsigned)v, l);
    const unsigned hi = (unsigned)__builtin_amdgcn_readlane((int)(unsigned)(v >> 32), l);
    return ((u64)hi << 32) | lo;
}

// ---------------------------------------------------------------------------
// Kernel 1: farthest point sampling + fused prepack — ROUND-11 VERBATIM
// (543us, proven floor: r8 more-waves, r9 cross-block, r10/r12 pk-math and
// tail restructures all regressed; r7 showed in-loop global stores free).
// ---------------------------------------------------------------------------
__global__ __launch_bounds__(512) void fps_kernel(const float* __restrict__ pc,
                                                  int* __restrict__ rep,
                                                  float4* __restrict__ ws4) {
    const int b    = blockIdx.x;
    const int t    = threadIdx.x;
    const int lane = t & 63;
    const int w    = t >> 6;

    __shared__ float4 sp[NPTS];                      // 128 KB
    __shared__ __align__(16) u64 keys[2][8];
    __shared__ int lrep[NGROUP];                     // 2 KB

    const float* base = pc + (size_t)b * NPTS * 6;
    float4* w4 = ws4 + ((size_t)b << 13);

    float px[16], py[16], pz[16], dmin[16];
#pragma unroll
    for (int j = 0; j < 16; ++j) {
        const int p = t * 16 + j;
        const float x = base[p * 6 + 0];
        const float y = base[p * 6 + 1];
        const float z = base[p * 6 + 2];
        px[j] = x; py[j] = y; pz[j] = z;
        const float4 f = make_float4(x, y, z, 0.0f);
        sp[p] = f;
        w4[p] = f;                                   // fused prepack
        dmin[j] = BIGF;
    }
    __syncthreads();

    int last = 0;
    for (int k = 0; k < NGROUP; ++k) {
        if (t == 0) lrep[k] = last;
        if (k == NGROUP - 1) break;

        const float4 L = sp[last];                   // one ds_read_b128, broadcast

        float bv = -1.0f;
        int   bi = 0;
#pragma unroll
        for (int j = 0; j < 16; ++j) {
            const float dx = __fsub_rn(px[j], L.x);
            const float dy = __fsub_rn(py[j], L.y);
            const float dz = __fsub_rn(pz[j], L.z);
            // ((dx^2 + dy^2) + dz^2), no FMA -> matches numpy fp32 (verified)
            const float d = __fadd_rn(__fadd_rn(__fmul_rn(dx, dx),
                                                __fmul_rn(dy, dy)),
                                      __fmul_rn(dz, dz));
            const float dm = fminf(dmin[j], d);
            dmin[j] = dm;
            if (dm > bv) { bv = dm; bi = t * 16 + j; }   // strict > keeps lowest idx
        }

        u64 key = ((u64)__float_as_uint(bv) << 13) | (unsigned)(8191 - bi);
        key = dpp_max_u64<0x111>(key);   // row_shr:1
        key = dpp_max_u64<0x112>(key);   // row_shr:2
        key = dpp_max_u64<0x114>(key);   // row_shr:4
        key = dpp_max_u64<0x118>(key);   // row_shr:8
        key = dpp_max_u64<0x142>(key);   // row_bcast:15
        key = dpp_max_u64<0x143>(key);   // row_bcast:31 -> lane 63 = wave max

        const int buf = k & 1;                       // parity dbuf -> 1 barrier/iter
        if (lane == 63) keys[buf][w] = key;
        __syncthreads();

        const ulonglong2* kp = (const ulonglong2*)keys[buf];   // 4x ds_read_b128
        const ulonglong2 k0 = kp[0], k1 = kp[1], k2 = kp[2], k3 = kp[3];
        const u64 best = umax64(umax64(umax64(k0.x, k0.y), umax64(k1.x, k1.y)),
                                umax64(umax64(k2.x, k2.y), umax64(k3.x, k3.y)));
        last = 8191 - (int)(best & 0x1FFFull);
    }

    __syncthreads();                                 // lrep visibility
    for (int j = t; j < NGROUP; j += 512)            // one coalesced write-out
        rep[b * NGROUP + j] = lrep[j];
}

// ---------------------------------------------------------------------------
// Kernel 2: 32-NN per sampled center + gathers — r11 machinery + round-14
// SOFTWARE PREFETCH: iteration i+1's two float4 loads issue BEFORE iteration
// i's d2/ballot/insert serialization, hiding the ~300cy load latency that the
// control-heavy loop prevented the compiler from pipelining. No pre-filter
// (r13 proved it neutral). Arithmetic & selection bit-identical to r11.
// ---------------------------------------------------------------------------
__global__ __launch_bounds__(256) void knn_kernel(const float* __restrict__ pc,
                                                  const float4* __restrict__ ws4,
                                                  const int* __restrict__ rep,
                                                  float* __restrict__ out) {
    const int tid  = threadIdx.x;
    const int lane = tid & 63;
    const int w    = tid >> 6;
    const int q    = blockIdx.x * 4 + w;       // 0 .. 8191
    const int b    = q >> 9;

    const float*  base  = pc  + (size_t)b * NPTS * 6;
    const float4* base4 = ws4 + ((size_t)b << 13);
    const int     r     = rep[q];

    const float4 Q = base4[r];
    const float qxf = Q.x, qyf = Q.y, qzf = Q.z;
    const double qx = (double)qxf, qy = (double)qyf, qz = (double)qzf;

    const u64 INFB = 0x7ff0000000000000ull;
    u64 vk = INFB;  int vi = 0x7fffffff;       // lane-distributed sorted list
    u64 tauk = INFB;                           // 32nd element's key (uniform)

    const int NIT = NPTS / 128;
    float4 A0 = base4[lane];
    float4 A1 = base4[lane + 64];

    for (int i = 0; i < NIT; ++i) {
        // prefetch next tile before this tile's serial phase
        const int nb = (i + 1 < NIT) ? (i + 1) * 128 + lane : lane;
        const float4 B0 = base4[nb];
        const float4 B1 = base4[nb + 64];

        const double dx0 = qx - (double)A0.x;
        const double dy0 = qy - (double)A0.y;
        const double dz0 = qz - (double)A0.z;
        const u64 kd0 = __double_as_longlong(dx0 * dx0 + dy0 * dy0 + dz0 * dz0);
        const double dx1 = qx - (double)A1.x;
        const double dy1 = qy - (double)A1.y;
        const double dz1 = qz - (double)A1.z;
        const u64 kd1 = __double_as_longlong(dx1 * dx1 + dy1 * dy1 + dz1 * dz1);

        u64 m0 = __ballot(kd0 < tauk);
        const u64 m1pre = __ballot(kd1 < tauk);

        if (m0 | m1pre) {
            while (m0) {
                const int l = __ffsll(m0) - 1;
                m0 &= m0 - 1;
                const u64 xk = rdlane64(kd0, l);   // SALU broadcast
                const int xi = i * 128 + l;        // affine: no shuffle
                const u64 pk = __shfl_up(vk, 1);
                const int pv = __shfl_up(vi, 1);
                const bool ltp = (lane > 0) && (xk < pk);
                const bool ltc = xk < vk;
                vk = ltp ? pk : (ltc ? xk : vk);
                vi = ltp ? pv : (ltc ? xi : vi);
            }
            tauk = rdlane64(vk, 31);               // refresh before half B
            u64 m1 = m1pre;
            while (m1) {
                const int l = __ffsll(m1) - 1;
                m1 &= m1 - 1;
                const u64 xk = rdlane64(kd1, l);
                if (xk < tauk) {                   // re-filter vs fresh tau
                    const int xi = i * 128 + 64 + l;
                    const u64 pk = __shfl_up(vk, 1);
                    const int pv = __shfl_up(vi, 1);
                    const bool ltp = (lane > 0) && (xk < pk);
                    const bool ltc = xk < vk;
                    vk = ltp ? pk : (ltc ? xk : vk);
                    vi = ltp ? pv : (ltc ? xi : vi);
                }
            }
            tauk = rdlane64(vk, 31);
        }

        A0 = B0; A1 = B1;
    }

    // ---- outputs ----
    const size_t NBH = (size_t)NBATCH * NGROUP * GSIZE * 6;   // neighborhood elems
    const size_t CEN = (size_t)NBATCH * NGROUP * 6;           // center elems

    if (lane == 0) {
#pragma unroll
        for (int c = 0; c < 6; ++c)
            out[NBH + (size_t)q * 6 + c] = base[r * 6 + c];
    }
    if (lane < GSIZE) {
        const int n = vi;                      // lane-sorted: position == lane
        out[NBH + CEN + (size_t)q * GSIZE + lane] = (float)n;

        const float* np_ = base + (size_t)n * 6;
        const size_t o = ((size_t)q * GSIZE + lane) * 6;
        out[o + 0] = __fsub_rn(np_[0], qxf);
        out[o + 1] = __fsub_rn(np_[1], qyf);
        out[o + 2] = __fsub_rn(np_[2], qzf);
        out[o + 3] = np_[3];
        out[o + 4] = np_[4];
        out[o + 5] = np_[5];
    }
}

extern "C" void kernel_launch(void* const* d_in, const int* in_sizes, int n_in,
                              void* d_out, int out_size, void* d_ws, size_t ws_size,
                              hipStream_t stream) {
    const float* pc  = (const float*)d_in[0];
    float*       out = (float*)d_out;
    int*         rep = (int*)d_ws;                              // 32 KB
    float4*      ws4 = (float4*)((char*)d_ws + 32 * 1024);      // 2 MB

    fps_kernel<<<NBATCH, 512, 0, stream>>>(pc, rep, ws4);
    knn_kernel<<<NBATCH * NGROUP / 4, 256, 0, stream>>>(pc, ws4, rep, out);
}

// Round 15
// 586.348 us; speedup vs baseline: 1.1946x; 1.1141x over previous
//
#include <hip/hip_runtime.h>

#define NPTS   8192
#define NBATCH 16
#define NGROUP 512
#define GSIZE  32
#define BIGF   1e10f

typedef unsigned long long u64;

// DPP max on a packed u64 key (round-7 proven).
template <int CTRL>
__device__ __forceinline__ u64 dpp_max_u64(u64 k) {
    const unsigned lo  = (unsigned)k;
    const unsigned hi  = (unsigned)(k >> 32);
    const unsigned slo = (unsigned)__builtin_amdgcn_update_dpp(0, (int)lo, CTRL, 0xF, 0xF, true);
    const unsigned shi = (unsigned)__builtin_amdgcn_update_dpp(0, (int)hi, CTRL, 0xF, 0xF, true);
    const u64 s = ((u64)shi << 32) | slo;
    return s > k ? s : k;
}

__device__ __forceinline__ u64 umax64(u64 a, u64 b) { return a > b ? a : b; }

// wave-uniform 64-bit readlane (SALU path, no LDS pipe)
__device__ __forceinline__ u64 rdlane64(u64 v, int l) {
    const unsigned lo = (unsigned)__builtin_amdgcn_readlane((int)(unsigned)v, l);
    const unsigned hi = (unsigned)__builtin_amdgcn_readlane((int)(unsigned)(v >> 32), l);
    return ((u64)hi << 32) | lo;
}

// ---------------------------------------------------------------------------
// Prepack: xyz as float4 for the knn scan, and rep = -1 sentinels (EVERY
// launch: the fused kernel's consumers poll rep >= 0).
// ---------------------------------------------------------------------------
__global__ __launch_bounds__(256) void prepack_kernel(const float* __restrict__ pc,
                                                      float4* __restrict__ ws4,
                                                      int* __restrict__ rep) {
    const int i = blockIdx.x * 256 + threadIdx.x;     // 0 .. 131071
    const float* s = pc + (size_t)i * 6;
    ws4[i] = make_float4(s[0], s[1], s[2], 0.0f);
    if (i < NBATCH * NGROUP) rep[i] = -1;
}

// ---------------------------------------------------------------------------
// knn scan for ONE query (r11 machinery verbatim: u64 keys = f64 bit order,
// readlane broadcasts, 2 points/lane/iter, lane-distributed sorted top-32).
// ---------------------------------------------------------------------------
__device__ __forceinline__ void knn_one(const float* __restrict__ base,
                                        const float4* __restrict__ base4,
                                        float* __restrict__ out,
                                        const int q, const int r, const int lane) {
    const float4 Q = base4[r];
    const float qxf = Q.x, qyf = Q.y, qzf = Q.z;
    const double qx = (double)qxf, qy = (double)qyf, qz = (double)qzf;

    const u64 INFB = 0x7ff0000000000000ull;
    u64 vk = INFB;  int vi = 0x7fffffff;
    u64 tauk = INFB;

    for (int i = 0; i < NPTS / 128; ++i) {
        const int p0 = i * 128 + lane;
        const float4 T0 = base4[p0];
        const float4 T1 = base4[p0 + 64];

        const double dx0 = qx - (double)T0.x;
        const double dy0 = qy - (double)T0.y;
        const double dz0 = qz - (double)T0.z;
        const u64 kd0 = __double_as_longlong(dx0 * dx0 + dy0 * dy0 + dz0 * dz0);
        const double dx1 = qx - (double)T1.x;
        const double dy1 = qy - (double)T1.y;
        const double dz1 = qz - (double)T1.z;
        const u64 kd1 = __double_as_longlong(dx1 * dx1 + dy1 * dy1 + dz1 * dz1);

        u64 m0 = __ballot(kd0 < tauk);
        const u64 m1pre = __ballot(kd1 < tauk);

        if (m0 | m1pre) {
            while (m0) {
                const int l = __ffsll(m0) - 1;
                m0 &= m0 - 1;
                const u64 xk = rdlane64(kd0, l);
                const int xi = i * 128 + l;
                const u64 pk = __shfl_up(vk, 1);
                const int pv = __shfl_up(vi, 1);
                const bool ltp = (lane > 0) && (xk < pk);
                const bool ltc = xk < vk;
                vk = ltp ? pk : (ltc ? xk : vk);
                vi = ltp ? pv : (ltc ? xi : vi);
            }
            tauk = rdlane64(vk, 31);
            u64 m1 = m1pre;
            while (m1) {
                const int l = __ffsll(m1) - 1;
                m1 &= m1 - 1;
                const u64 xk = rdlane64(kd1, l);
                if (xk < tauk) {
                    const int xi = i * 128 + 64 + l;
                    const u64 pk = __shfl_up(vk, 1);
                    const int pv = __shfl_up(vi, 1);
                    const bool ltp = (lane > 0) && (xk < pk);
                    const bool ltc = xk < vk;
                    vk = ltp ? pk : (ltc ? xk : vk);
                    vi = ltp ? pv : (ltc ? xi : vi);
                }
            }
            tauk = rdlane64(vk, 31);
        }
    }

    const size_t NBH = (size_t)NBATCH * NGROUP * GSIZE * 6;
    const size_t CEN = (size_t)NBATCH * NGROUP * 6;

    if (lane == 0) {
#pragma unroll
        for (int c = 0; c < 6; ++c)
            out[NBH + (size_t)q * 6 + c] = base[r * 6 + c];
    }
    if (lane < GSIZE) {
        const int n = vi;
        out[NBH + CEN + (size_t)q * GSIZE + lane] = (float)n;

        const float* np_ = base + (size_t)n * 6;
        const size_t o = ((size_t)q * GSIZE + lane) * 6;
        out[o + 0] = __fsub_rn(np_[0], qxf);
        out[o + 1] = __fsub_rn(np_[1], qyf);
        out[o + 2] = __fsub_rn(np_[2], qzf);
        out[o + 3] = np_[3];
        out[o + 4] = np_[4];
        out[o + 5] = np_[5];
    }
}

// ---------------------------------------------------------------------------
// Fused producer/consumer. 256 blocks x 512 threads, 130KB LDS -> exactly
// 1 block/CU, all 256 co-resident (deadlock-free by capacity; fps CUs host
// no knn waves -> zero interference).
//  blocks 0..15  : fps for batch=bid (r11 body verbatim), publishing
//                  rep[b][k] per iteration via relaxed agent atomic store
//                  (the value IS the only cross-block data; r6 proved
//                  in-loop global stores are free).
//  blocks 16..255: 15 blocks per batch; each of 8 waves handles queries
//                  m = j*8+w (+120 stride), polling rep[q] >= 0 then running
//                  the exact r11 scan. Queries arrive in fps iteration
//                  order, so waves drain as fps progresses; tail = last
//                  query's scan (~15us) after fps ends.
// ---------------------------------------------------------------------------
__global__ __launch_bounds__(512) void fused_kernel(const float* __restrict__ pc,
                                                    const float4* __restrict__ ws4,
                                                    int* __restrict__ rep,
                                                    float* __restrict__ out) {
    const int bid  = blockIdx.x;
    const int t    = threadIdx.x;
    const int lane = t & 63;
    const int w    = t >> 6;

    __shared__ float4 sp[NPTS];                      // 128 KB (also sizes knn blocks)
    __shared__ __align__(16) u64 keys[2][8];

    if (bid < NBATCH) {
        // ---------------- FPS (r11 verbatim + per-iter rep publish) ----------
        const int b = bid;
        const float* base = pc + (size_t)b * NPTS * 6;

        float px[16], py[16], pz[16], dmin[16];
#pragma unroll
        for (int j = 0; j < 16; ++j) {
            const int p = t * 16 + j;
            const float x = base[p * 6 + 0];
            const float y = base[p * 6 + 1];
            const float z = base[p * 6 + 2];
            px[j] = x; py[j] = y; pz[j] = z;
            sp[p] = make_float4(x, y, z, 0.0f);
            dmin[j] = BIGF;
        }
        __syncthreads();

        int last = 0;
        for (int k = 0; k < NGROUP; ++k) {
            if (t == 0)
                __hip_atomic_store(rep + b * NGROUP + k, last,
                                   __ATOMIC_RELAXED, __HIP_MEMORY_SCOPE_AGENT);
            if (k == NGROUP - 1) break;

            const float4 L = sp[last];               // one ds_read_b128, broadcast

            float bv = -1.0f;
            int   bi = 0;
#pragma unroll
            for (int j = 0; j < 16; ++j) {
                const float dx = __fsub_rn(px[j], L.x);
                const float dy = __fsub_rn(py[j], L.y);
                const float dz = __fsub_rn(pz[j], L.z);
                // ((dx^2 + dy^2) + dz^2), no FMA -> matches numpy fp32 (verified)
                const float d = __fadd_rn(__fadd_rn(__fmul_rn(dx, dx),
                                                    __fmul_rn(dy, dy)),
                                          __fmul_rn(dz, dz));
                const float dm = fminf(dmin[j], d);
                dmin[j] = dm;
                if (dm > bv) { bv = dm; bi = t * 16 + j; }   // strict > keeps lowest idx
            }

            u64 key = ((u64)__float_as_uint(bv) << 13) | (unsigned)(8191 - bi);
            key = dpp_max_u64<0x111>(key);   // row_shr:1
            key = dpp_max_u64<0x112>(key);   // row_shr:2
            key = dpp_max_u64<0x114>(key);   // row_shr:4
            key = dpp_max_u64<0x118>(key);   // row_shr:8
            key = dpp_max_u64<0x142>(key);   // row_bcast:15
            key = dpp_max_u64<0x143>(key);   // row_bcast:31 -> lane 63 = wave max

            const int buf = k & 1;                   // parity dbuf -> 1 barrier/iter
            if (lane == 63) keys[buf][w] = key;
            __syncthreads();

            const ulonglong2* kp = (const ulonglong2*)keys[buf];   // 4x ds_read_b128
            const ulonglong2 k0 = kp[0], k1 = kp[1], k2 = kp[2], k3 = kp[3];
            const u64 best = umax64(umax64(umax64(k0.x, k0.y), umax64(k1.x, k1.y)),
                                    umax64(umax64(k2.x, k2.y), umax64(k3.x, k3.y)));
            last = 8191 - (int)(best & 0x1FFFull);
        }
    } else {
        // ---------------- KNN consumers -------------------------------------
        const int kb = bid - NBATCH;                 // 0..239
        const int b  = kb / 15;                      // batch
        const int j  = kb % 15;                      // block-in-batch
        const int m0 = j * 8 + w;                    // 0..119 (wave's first query)

        const float*  base  = pc  + (size_t)b * NPTS * 6;
        const float4* base4 = ws4 + ((size_t)b << 13);

        for (int m = m0; m < NGROUP; m += 120) {
            const int q = b * NGROUP + m;
            int rv;
            for (;;) {
                rv = __hip_atomic_load(rep + q, __ATOMIC_RELAXED,
                                       __HIP_MEMORY_SCOPE_AGENT);
                if (rv >= 0) break;
                __builtin_amdgcn_s_sleep(8);
            }
            knn_one(base, base4, out, q, rv, lane);
        }
    }
}

extern "C" void kernel_launch(void* const* d_in, const int* in_sizes, int n_in,
                              void* d_out, int out_size, void* d_ws, size_t ws_size,
                              hipStream_t stream) {
    const float* pc  = (const float*)d_in[0];
    float*       out = (float*)d_out;
    int*         rep = (int*)d_ws;                              // 32 KB
    float4*      ws4 = (float4*)((char*)d_ws + 32 * 1024);      // 2 MB

    prepack_kernel<<<NBATCH * NPTS / 256, 256, 0, stream>>>(pc, ws4, rep);
    fused_kernel<<<NBATCH + 240, 512, 0, stream>>>(pc, ws4, rep, out);
}

// Round 16
// 582.312 us; speedup vs baseline: 1.2029x; 1.0069x over previous
//
#include <hip/hip_runtime.h>

#define NPTS   8192
#define NBATCH 16
#define NGROUP 512
#define GSIZE  32
#define BIGF   1e10f

typedef unsigned long long u64;

// DPP max on a packed u64 key (round-7 proven).
template <int CTRL>
__device__ __forceinline__ u64 dpp_max_u64(u64 k) {
    const unsigned lo  = (unsigned)k;
    const unsigned hi  = (unsigned)(k >> 32);
    const unsigned slo = (unsigned)__builtin_amdgcn_update_dpp(0, (int)lo, CTRL, 0xF, 0xF, true);
    const unsigned shi = (unsigned)__builtin_amdgcn_update_dpp(0, (int)hi, CTRL, 0xF, 0xF, true);
    const u64 s = ((u64)shi << 32) | slo;
    return s > k ? s : k;
}

__device__ __forceinline__ u64 umax64(u64 a, u64 b) { return a > b ? a : b; }

// wave-uniform 64-bit readlane (SALU path, no LDS pipe)
__device__ __forceinline__ u64 rdlane64(u64 v, int l) {
    const unsigned lo = (unsigned)__builtin_amdgcn_readlane((int)(unsigned)v, l);
    const unsigned hi = (unsigned)__builtin_amdgcn_readlane((int)(unsigned)(v >> 32), l);
    return ((u64)hi << 32) | lo;
}

// ---------------------------------------------------------------------------
// knn scan for ONE query — r11 machinery verbatim (u64 keys = f64 bit order,
// readlane broadcasts, 2 points/lane/iter, lane-distributed sorted top-32),
// but reading the staged LDS copy of the batch's xyz (conflict-free
// ds_read_b128) instead of L2. Same fp32 inputs -> bit-identical keys/order.
// ---------------------------------------------------------------------------
__device__ __forceinline__ void knn_one(const float* __restrict__ base,
                                        const float4* sp,
                                        float* __restrict__ out,
                                        const int q, const int r, const int lane) {
    const float4 Q = sp[r];
    const float qxf = Q.x, qyf = Q.y, qzf = Q.z;
    const double qx = (double)qxf, qy = (double)qyf, qz = (double)qzf;

    const u64 INFB = 0x7ff0000000000000ull;
    u64 vk = INFB;  int vi = 0x7fffffff;
    u64 tauk = INFB;

    for (int i = 0; i < NPTS / 128; ++i) {
        const int p0 = i * 128 + lane;
        const float4 T0 = sp[p0];
        const float4 T1 = sp[p0 + 64];

        const double dx0 = qx - (double)T0.x;
        const double dy0 = qy - (double)T0.y;
        const double dz0 = qz - (double)T0.z;
        const u64 kd0 = __double_as_longlong(dx0 * dx0 + dy0 * dy0 + dz0 * dz0);
        const double dx1 = qx - (double)T1.x;
        const double dy1 = qy - (double)T1.y;
        const double dz1 = qz - (double)T1.z;
        const u64 kd1 = __double_as_longlong(dx1 * dx1 + dy1 * dy1 + dz1 * dz1);

        u64 m0 = __ballot(kd0 < tauk);
        const u64 m1pre = __ballot(kd1 < tauk);

        if (m0 | m1pre) {
            while (m0) {
                const int l = __ffsll(m0) - 1;
                m0 &= m0 - 1;
                const u64 xk = rdlane64(kd0, l);
                const int xi = i * 128 + l;
                const u64 pk = __shfl_up(vk, 1);
                const int pv = __shfl_up(vi, 1);
                const bool ltp = (lane > 0) && (xk < pk);
                const bool ltc = xk < vk;
                vk = ltp ? pk : (ltc ? xk : vk);
                vi = ltp ? pv : (ltc ? xi : vi);
            }
            tauk = rdlane64(vk, 31);
            u64 m1 = m1pre;
            while (m1) {
                const int l = __ffsll(m1) - 1;
                m1 &= m1 - 1;
                const u64 xk = rdlane64(kd1, l);
                if (xk < tauk) {
                    const int xi = i * 128 + 64 + l;
                    const u64 pk = __shfl_up(vk, 1);
                    const int pv = __shfl_up(vi, 1);
                    const bool ltp = (lane > 0) && (xk < pk);
                    const bool ltc = xk < vk;
                    vk = ltp ? pk : (ltc ? xk : vk);
                    vi = ltp ? pv : (ltc ? xi : vi);
                }
            }
            tauk = rdlane64(vk, 31);
        }
    }

    const size_t NBH = (size_t)NBATCH * NGROUP * GSIZE * 6;
    const size_t CEN = (size_t)NBATCH * NGROUP * 6;

    if (lane == 0) {
#pragma unroll
        for (int c = 0; c < 6; ++c)
            out[NBH + (size_t)q * 6 + c] = base[r * 6 + c];
    }
    if (lane < GSIZE) {
        const int n = vi;
        out[NBH + CEN + (size_t)q * GSIZE + lane] = (float)n;

        const float* np_ = base + (size_t)n * 6;
        const size_t o = ((size_t)q * GSIZE + lane) * 6;
        out[o + 0] = __fsub_rn(np_[0], qxf);
        out[o + 1] = __fsub_rn(np_[1], qyf);
        out[o + 2] = __fsub_rn(np_[2], qzf);
        out[o + 3] = np_[3];
        out[o + 4] = np_[4];
        out[o + 5] = np_[5];
    }
}

// ---------------------------------------------------------------------------
// Fused producer/consumer (r15 skeleton, 586us). 256 blocks x 512 threads,
// ~129KB LDS -> 1 block/CU, all 256 co-resident (deadlock-free by capacity).
//  blocks 0..15  : fps for batch=bid (r11 body), publishing rep[b][k] per
//                  iteration via relaxed agent atomic store.
//  blocks 16..255: 15 blocks/batch. ROUND-16: each consumer block first
//                  stages its batch's xyz into its OWN LDS (idle in r15),
//                  then waves poll rep and scan from LDS — deleting the
//                  ~1GB/launch consumer L2 flood (interference suspect).
// rep is memset to -1 on the stream before launch (graph-safe).
// ---------------------------------------------------------------------------
__global__ __launch_bounds__(512) void fused_kernel(const float* __restrict__ pc,
                                                    int* __restrict__ rep,
                                                    float* __restrict__ out) {
    const int bid  = blockIdx.x;
    const int t    = threadIdx.x;
    const int lane = t & 63;
    const int w    = t >> 6;

    __shared__ float4 sp[NPTS];                      // 128 KB
    __shared__ __align__(16) u64 keys[2][8];

    if (bid < NBATCH) {
        // ---------------- FPS producer (r11 body + per-iter publish) --------
        const int b = bid;
        const float* base = pc + (size_t)b * NPTS * 6;

        float px[16], py[16], pz[16], dmin[16];
#pragma unroll
        for (int j = 0; j < 16; ++j) {
            const int p = t * 16 + j;
            const float x = base[p * 6 + 0];
            const float y = base[p * 6 + 1];
            const float z = base[p * 6 + 2];
            px[j] = x; py[j] = y; pz[j] = z;
            sp[p] = make_float4(x, y, z, 0.0f);
            dmin[j] = BIGF;
        }
        __syncthreads();

        int last = 0;
        for (int k = 0; k < NGROUP; ++k) {
            if (t == 0)
                __hip_atomic_store(rep + b * NGROUP + k, last,
                                   __ATOMIC_RELAXED, __HIP_MEMORY_SCOPE_AGENT);
            if (k == NGROUP - 1) break;

            const float4 L = sp[last];               // one ds_read_b128, broadcast

            float bv = -1.0f;
            int   bi = 0;
#pragma unroll
            for (int j = 0; j < 16; ++j) {
                const float dx = __fsub_rn(px[j], L.x);
                const float dy = __fsub_rn(py[j], L.y);
                const float dz = __fsub_rn(pz[j], L.z);
                // ((dx^2 + dy^2) + dz^2), no FMA -> matches numpy fp32 (verified)
                const float d = __fadd_rn(__fadd_rn(__fmul_rn(dx, dx),
                                                    __fmul_rn(dy, dy)),
                                          __fmul_rn(dz, dz));
                const float dm = fminf(dmin[j], d);
                dmin[j] = dm;
                if (dm > bv) { bv = dm; bi = t * 16 + j; }   // strict > keeps lowest idx
            }

            u64 key = ((u64)__float_as_uint(bv) << 13) | (unsigned)(8191 - bi);
            key = dpp_max_u64<0x111>(key);   // row_shr:1
            key = dpp_max_u64<0x112>(key);   // row_shr:2
            key = dpp_max_u64<0x114>(key);   // row_shr:4
            key = dpp_max_u64<0x118>(key);   // row_shr:8
            key = dpp_max_u64<0x142>(key);   // row_bcast:15
            key = dpp_max_u64<0x143>(key);   // row_bcast:31 -> lane 63 = wave max

            const int buf = k & 1;                   // parity dbuf -> 1 barrier/iter
            if (lane == 63) keys[buf][w] = key;
            __syncthreads();

            const ulonglong2* kp = (const ulonglong2*)keys[buf];   // 4x ds_read_b128
            const ulonglong2 k0 = kp[0], k1 = kp[1], k2 = kp[2], k3 = kp[3];
            const u64 best = umax64(umax64(umax64(k0.x, k0.y), umax64(k1.x, k1.y)),
                                    umax64(umax64(k2.x, k2.y), umax64(k3.x, k3.y)));
            last = 8191 - (int)(best & 0x1FFFull);
        }
    } else {
        // ---------------- KNN consumers -------------------------------------
        const int kb = bid - NBATCH;                 // 0..239
        const int b  = kb / 15;                      // batch
        const int j  = kb % 15;                      // block-in-batch
        const int m0 = j * 8 + w;                    // 0..119 (wave's first query)

        const float* base = pc + (size_t)b * NPTS * 6;

        // stage the whole batch's xyz into this block's LDS (idle time:
        // happens before fps publishes anything)
#pragma unroll
        for (int jj = 0; jj < NPTS / 512; ++jj) {
            const int p = jj * 512 + t;
            sp[p] = make_float4(base[p * 6 + 0], base[p * 6 + 1],
                                base[p * 6 + 2], 0.0f);
        }
        __syncthreads();

        for (int m = m0; m < NGROUP; m += 120) {
            const int q = b * NGROUP + m;
            int rv;
            for (;;) {
                rv = __hip_atomic_load(rep + q, __ATOMIC_RELAXED,
                                       __HIP_MEMORY_SCOPE_AGENT);
                if (rv >= 0) break;
                __builtin_amdgcn_s_sleep(8);
            }
            knn_one(base, sp, out, q, rv, lane);
        }
    }
}

extern "C" void kernel_launch(void* const* d_in, const int* in_sizes, int n_in,
                              void* d_out, int out_size, void* d_ws, size_t ws_size,
                              hipStream_t stream) {
    const float* pc  = (const float*)d_in[0];
    float*       out = (float*)d_out;
    int*         rep = (int*)d_ws;                   // 32 KB

    // rep = -1 sentinels (0xFF bytes) — stream op, graph-capture-safe
    hipMemsetAsync(rep, 0xFF, (size_t)NBATCH * NGROUP * sizeof(int), stream);

    fused_kernel<<<NBATCH + 240, 512, 0, stream>>>(pc, rep, out);
}